// Round 18
// baseline (38.970 us; speedup 1.0000x reference)
//
#include <hip/hip_runtime.h>
#include <cstdint>

// EdgeGateAttention, MI355X — round 16 kernel, third submission (rounds 16
// and 17 both hit UnresponsiveContainer infra failures before any GPU work;
// no signal either time).  Occupancy push on attention.
// r15 post-mortem: LDS-free slightly negative (L2 latency per iter > barrier
// cost).  attn stuck 22-26us across 5 structural variants at 4 waves/SIMD
// (VGPR 112, grid 1024 = exactly 4 blocks/CU) -> latency-bound, occupancy is
// the unpulled lever.  This round: MSA=8 (2048 blocks, 8/CU queue), MT=128
// K-only LDS staging (8KB, 4 staging VGPR), V direct-from-global (r15 chunk
// layout), __launch_bounds__(256,5) -> 5 waves/SIMD.
//
// Gate skip (validated r1): gate renorm makes it identity to O(1e-8).
// Softmax: raw v_exp_f32, no max subtraction; 0.25*log2(e) folded into Q.
// l from ones-column (d=16) of the PV MFMA.

namespace {
constexpr int B  = 2;
constexpr int C  = 64;
constexpr int NH = 4;
constexpr int HD = 16;
constexpr int N  = 4096;
constexpr int MSA = 8;              // attention m-split (2048 blocks)

constexpr size_t QKV1     = (size_t)B * NH * N * HD;        // 524288
constexpr size_t KB_OFF   = QKV1;
constexpr size_t VT_OFF   = 2 * QKV1;
constexpr size_t PO_OFF_U = 3 * QKV1;                       // ushort idx
constexpr size_t PO_SZ    = (size_t)B * NH * MSA * N * HD;  // 4194304 ushorts
constexpr size_t PL_OFF_F = (PO_OFF_U + PO_SZ) / 2;         // float idx
constexpr float QSCALE = 0.36067376022224085f;              // 0.25 * log2(e)
}

typedef short bf16x8 __attribute__((ext_vector_type(8)));
typedef float f32x16 __attribute__((ext_vector_type(16)));
typedef int   i32x4  __attribute__((ext_vector_type(4)));

__device__ __forceinline__ unsigned short f2bf(float f) {  // RNE f32->bf16
  unsigned u = __float_as_uint(f);
  u = (u + 0x7fffu + ((u >> 16) & 1u)) >> 16;
  return (unsigned short)u;
}
__device__ __forceinline__ int cvtpk(float lo, float hi) {
  int r;
  asm("v_cvt_pk_bf16_f32 %0, %1, %2" : "=v"(r) : "v"(lo), "v"(hi));
  return r;
}
__device__ __forceinline__ float fexp2(float x) {  // raw v_exp_f32
#if __has_builtin(__builtin_amdgcn_exp2f)
  return __builtin_amdgcn_exp2f(x);
#else
  float r;
  asm("v_exp_f32 %0, %1" : "=v"(r) : "v"(x));
  return r;
#endif
}
__device__ __forceinline__ float frcp(float x) {
#if __has_builtin(__builtin_amdgcn_rcpf)
  return __builtin_amdgcn_rcpf(x);
#else
  float r;
  asm("v_rcp_f32 %0, %1" : "=v"(r) : "v"(x));
  return r;
#endif
}
__device__ __forceinline__ void plswap(int a, int b, int h, int& x, int& y) {
#if __has_builtin(__builtin_amdgcn_permlane32_swap)
  (void)h;
  auto r = __builtin_amdgcn_permlane32_swap(a, b, false, false);
  x = r[0]; y = r[1];
#else
  const int ea = __shfl_xor(a, 32), eb = __shfl_xor(b, 32);
  x = h ? eb : a;
  y = h ? b : ea;
#endif
}

// ---------------------------------------------------------------------------
// Kernel 1: QKV GEMM (r15, proven).  Grid (N/64, B, 3): z=0 q, 1 k, 2 v.
// k: chunk order [bh][n/32][half][n%32] (16B chunks).
// v: chunk order [bh][n/32][sub(4 m-octets)][d(16)][8m] (16B chunks).
// ---------------------------------------------------------------------------
__global__ __launch_bounds__(256) void qkv_mfma_kernel(
    const float* __restrict__ x, const float* __restrict__ w,
    const float* __restrict__ bias, unsigned short* __restrict__ qb,
    unsigned short* __restrict__ kb, unsigned short* __restrict__ vtb) {
  __shared__ char wl[64 * 128];   // W slice bf16, byte (2c)^((j&7)<<4)
  __shared__ char tl[4 * 2048];   // per-wave transpose buffers
  const int tid = threadIdx.x;
  const int lane = tid & 63, wid = tid >> 6;
  const int l31 = lane & 31, h = lane >> 5;
  const int nw = wid >> 1, jw = wid & 1;
  const int b = blockIdx.y, n0 = blockIdx.x * 64, z = blockIdx.z;

#pragma unroll
  for (int k = 0; k < 8; ++k) {   // stage W slice (64 rows x 64 c)
    const int p = tid + k * 256;
    const int j = p >> 5, c2 = (p & 31) * 2;
    const float2 wv = *(const float2*)(w + ((size_t)z * 64 + j) * 64 + c2);
    *(int*)(wl + j * 128 + ((2 * c2) ^ ((j & 7) << 4))) = cvtpk(wv.x, wv.y);
  }

  const int nA = n0 + nw * 32 + l31;
  bf16x8 af[4];
#pragma unroll
  for (int kk = 0; kk < 4; ++kk) {  // A-frags from global (coalesced over n)
    float e[8];
#pragma unroll
    for (int i = 0; i < 8; ++i)
      e[i] = x[((size_t)b * C + kk * 16 + h * 8 + i) * N + nA];
    i32x4 pk = {cvtpk(e[0], e[1]), cvtpk(e[2], e[3]),
                cvtpk(e[4], e[5]), cvtpk(e[6], e[7])};
    af[kk] = __builtin_bit_cast(bf16x8, pk);
  }
  __syncthreads();

  const int j = jw * 32 + l31;      // j within z-slice (0..63)
  f32x16 acc = {};
#pragma unroll
  for (int kk = 0; kk < 4; ++kk) {
    bf16x8 bf =
        *(const bf16x8*)(wl + j * 128 + ((kk * 32 + h * 16) ^ ((j & 7) << 4)));
    acc = __builtin_amdgcn_mfma_f32_32x32x16_bf16(af[kk], bf, acc, 0, 0, 0);
  }
  const float bj = bias[z * 64 + j];
  char* myt = tl + wid * 2048;
  const int mt32 = (n0 >> 5) + nw;    // 32-row tile index in N

  if (z < 2) {  // q/k; LDS [32n][32j] bf16 (rows 64B)
    const float sc = (z == 0) ? QSCALE : 1.0f;
#pragma unroll
    for (int r = 0; r < 16; ++r) {
      const int n = (r & 3) + 8 * (r >> 2) + 4 * h;
      *(unsigned short*)(myt + n * 64 + l31 * 2) = f2bf((acc[r] + bj) * sc);
    }
#pragma unroll
    for (int u = 0; u < 2; ++u) {   // 128 chunks: (n, 8-j group)
      const int chunk = lane * 2 + u;
      const int n = chunk >> 2, c = chunk & 3;
      const uint4 vv = *(const uint4*)(myt + n * 64 + c * 16);
      const int jj = jw * 32 + c * 8;          // j-offset in 0..63
      const int hh = jj >> 4, half = (jj >> 3) & 1;
      const int bh = b * NH + hh;
      if (z == 0) {   // q: [bh][n][16]
        *(uint4*)(qb + ((size_t)bh * N + n0 + nw * 32 + n) * HD + half * 8) = vv;
      } else {        // k: chunk order [bh][tile32][half][r]
        const size_t ck = (size_t)bh * 8192 + (size_t)mt32 * 64 + half * 32 + n;
        *(uint4*)(kb + ck * 8) = vv;
      }
    }
  } else {      // v: chunk order [bh][tile32][sub][d][8m]; LDS [32j][32n]
#pragma unroll
    for (int p = 0; p < 8; ++p) {
      const int r = 2 * p;
      const int n = (r & 3) + 8 * (r >> 2) + 4 * h;  // even
      *(int*)(myt + l31 * 64 + n * 2) = cvtpk(acc[r] + bj, acc[r + 1] + bj);
    }
#pragma unroll
    for (int u = 0; u < 2; ++u) {   // 128 chunks: (j, 8-n octet)
      const int chunk = lane * 2 + u;
      const int jj = chunk >> 2, c = chunk & 3;   // c = m-octet (sub)
      const uint4 vv = *(const uint4*)(myt + jj * 64 + c * 16);
      const int vj = jw * 32 + jj;             // 0..63
      const int hh = vj >> 4, hd = vj & 15;
      const size_t ck =
          (((size_t)(b * NH + hh) * 128 + mt32) * 4 + c) * 16 + hd;
      *(uint4*)(vtb + ck * 8) = vv;
    }
  }
}

// ---------------------------------------------------------------------------
// Kernel 2: attention.  Grid (N/128, MSA=8, B*NH) = 2048 blocks, 4 waves x
// 32 q-rows, __launch_bounds__(256,5) -> 5 waves/SIMD.
// K: MT=128 tiles double-buffered in 8KB LDS (1 uint4 staging reg/thread;
// conflict-free contiguous reads).  V: direct from global, r15 chunk layout.
// ---------------------------------------------------------------------------
__global__ __launch_bounds__(256, 5) void attn_mfma_kernel(
    const unsigned short* __restrict__ qb, const unsigned short* __restrict__ kb,
    const unsigned short* __restrict__ vtb, unsigned short* __restrict__ part_o,
    float* __restrict__ part_l) {
  __shared__ char ldsb[2 * 4096];   // K tiles only (+ epilogue reuse)
  const int tid  = threadIdx.x;
  const int lane = tid & 63;
  const int wid  = tid >> 6;
  const int l31  = lane & 31;
  const int h    = lane >> 5;
  const int bh = blockIdx.z;
  const int ms = blockIdx.y;
  const int q0 = blockIdx.x * 128 + wid * 32;
  const int m0 = ms * (N / MSA);       // 512-row m-chunk
  constexpr int NT = (N / MSA) / 128;  // 4 K-tiles of 128 m

  bf16x8 qf;
  {
    const uint4 qv =
        *(const uint4*)(qb + (((size_t)bh * N) + q0 + l31) * HD + h * 8);
    qf = __builtin_bit_cast(bf16x8, qv);
  }
  // K chunk base for (bh, m0): tile t = 256 chunks, LINEAR.
  const unsigned short* kgp = kb + ((size_t)bh * 8192 + (size_t)(m0 >> 5) * 64) * 8;
  // V per-lane pointer (d = l31 < 16): stride 512 ushorts per 32-m iter.
  const unsigned short* vp =
      vtb + ((((size_t)bh * 128 + (m0 >> 5)) * 4 + h) * 16 + l31) * 8;

  {  // prologue: stage K tile 0
    const uint4 k0 = *(const uint4*)(kgp + (size_t)tid * 8);
    *(uint4*)(ldsb + tid * 16) = k0;
  }
  __syncthreads();

  const int onef = (l31 == HD) ? 0x3F803F80 : 0;
  const i32x4 onev = {onef, onef, onef, onef};
  const bf16x8 vcst = __builtin_bit_cast(bf16x8, onev);

  f32x16 acc = {};
  int cur = 0;
  for (int t = 0; t < NT; ++t) {
    uint4 k0{};
    const bool pre = (t + 1 < NT);
    if (pre)  // issue next K tile load; hides under this tile's compute
      k0 = *(const uint4*)(kgp + ((size_t)(t + 1) * 256 + tid) * 8);
    const char* kbase = ldsb + cur * 4096;
#pragma unroll
    for (int cc = 0; cc < 4; ++cc) {
      const int it = t * 4 + cc;
      // conflict-free: half-wave reads 512B contiguous
      bf16x8 kf = *(const bf16x8*)(kbase + (cc * 64 + h * 32 + l31) * 16);
      f32x16 zv = {};
      f32x16 st = __builtin_amdgcn_mfma_f32_32x32x16_bf16(kf, qf, zv, 0, 0, 0);
      bf16x8 vf1, vf2;
      if (l31 < HD) {
        vf1 = *(const bf16x8*)(vp + (size_t)it * 512);
        vf2 = *(const bf16x8*)(vp + (size_t)it * 512 + 256);
      } else {  // d=16: ones column -> acc col 16 = sum(p) = l
        vf1 = vcst;
        vf2 = vcst;
      }
      int dw[8];
#pragma unroll
      for (int jj = 0; jj < 8; ++jj)
        dw[jj] = cvtpk(fexp2(st[2 * jj]), fexp2(st[2 * jj + 1]));
      int w0, w1, w2, w3, w4, w5, w6, w7;
      plswap(dw[0], dw[2], h, w0, w2);
      plswap(dw[1], dw[3], h, w1, w3);
      plswap(dw[4], dw[6], h, w4, w6);
      plswap(dw[5], dw[7], h, w5, w7);
      const i32x4 a1 = {w0, w1, w2, w3};
      const i32x4 a2 = {w4, w5, w6, w7};
      acc = __builtin_amdgcn_mfma_f32_32x32x16_bf16(
          __builtin_bit_cast(bf16x8, a1), vf1, acc, 0, 0, 0);
      acc = __builtin_amdgcn_mfma_f32_32x32x16_bf16(
          __builtin_bit_cast(bf16x8, a2), vf2, acc, 0, 0, 0);
    }
    if (pre) *(uint4*)(ldsb + (cur ^ 1) * 4096 + tid * 16) = k0;
    __syncthreads();
    cur ^= 1;
  }

  const size_t pbase = ((size_t)bh * MSA + ms) * N + q0;
  if (l31 == HD) {
#pragma unroll
    for (int r = 0; r < 16; ++r)
      part_l[pbase + (r & 3) + 8 * (r >> 2) + 4 * h] = acc[r];
  }
  char* myt = ldsb + wid * 1024;    // [32q][16d] bf16, per-wave (reuse)
  if (l31 < HD) {
#pragma unroll
    for (int r = 0; r < 16; ++r) {
      const int q = (r & 3) + 8 * (r >> 2) + 4 * h;
      *(unsigned short*)(myt + q * 32 + l31 * 2) = f2bf(acc[r]);
    }
  }
  __syncthreads();
  const int qr = lane >> 1, half = lane & 1;
  const uint4 vv = *(const uint4*)(myt + qr * 32 + half * 16);
  *(uint4*)(part_o + (pbase + qr) * HD + half * 8) = vv;
}

// ---------------------------------------------------------------------------
// Kernel 3: fused combine + projection.  Grid (N/32, B); MSA=8 combine.
// ---------------------------------------------------------------------------
__global__ __launch_bounds__(128) void proj_mfma_kernel(
    const unsigned short* __restrict__ part_o, const float* __restrict__ part_l,
    const float* __restrict__ pw, const float* __restrict__ pb,
    float* __restrict__ out) {
  __shared__ char al[32 * 128];
  __shared__ char bl[64 * 128];
  __shared__ char tl[2 * 4096];
  __shared__ float linv[128];
  const int tid = threadIdx.x;
  const int lane = tid & 63, wid = tid >> 6;
  const int l31 = lane & 31, h = lane >> 5;
  const int b = blockIdx.y, n0 = blockIdx.x * 32;

  {
    const int hh = tid >> 5, n = tid & 31;
    const size_t base = ((size_t)(b * NH + hh) * MSA) * N + n0 + n;
    float l = 0.f;
#pragma unroll
    for (int ms = 0; ms < MSA; ++ms) l += part_l[base + (size_t)ms * N];
    linv[tid] = frcp(l);
  }
#pragma unroll
  for (int k = 0; k < 16; ++k) {
    const int p = tid + k * 128;
    const int cR = p >> 5, d2 = (p & 31) * 2;
    const float2 wv = *(const float2*)(pw + cR * 64 + d2);
    *(int*)(bl + cR * 128 + ((2 * d2) ^ ((cR & 7) << 4))) = cvtpk(wv.x, wv.y);
  }
  __syncthreads();

#pragma unroll
  for (int u = 0; u < 2; ++u) {
    const int chunk = tid * 2 + u;
    const int hh = chunk >> 6, half = (chunk >> 5) & 1, n = chunk & 31;
    const unsigned short* src =
        part_o + (((size_t)(b * NH + hh) * MSA) * N + n0 + n) * HD + half * 8;
    float s[8] = {0.f, 0.f, 0.f, 0.f, 0.f, 0.f, 0.f, 0.f};
#pragma unroll
    for (int ms = 0; ms < MSA; ++ms) {
      const uint4 v = *(const uint4*)(src + (size_t)ms * N * HD);
      const unsigned uu[4] = {v.x, v.y, v.z, v.w};
#pragma unroll
      for (int q = 0; q < 4; ++q) {
        s[2 * q]     += __uint_as_float(uu[q] << 16);
        s[2 * q + 1] += __uint_as_float(uu[q] & 0xffff0000u);
      }
    }
    const float iv = linv[hh * 32 + n];
    const i32x4 pk = {cvtpk(s[0] * iv, s[1] * iv), cvtpk(s[2] * iv, s[3] * iv),
                      cvtpk(s[4] * iv, s[5] * iv), cvtpk(s[6] * iv, s[7] * iv)};
    const int d = hh * 16 + half * 8;
    *(i32x4*)(al + n * 128 + ((2 * d) ^ ((n & 7) << 4))) = pk;
  }
  __syncthreads();

  bf16x8 af[4];
#pragma unroll
  for (int kk = 0; kk < 4; ++kk)
    af[kk] = *(const bf16x8*)(al + l31 * 128 +
                              ((kk * 32 + h * 16) ^ ((l31 & 7) << 4)));
  const int c = wid * 32 + l31;
  f32x16 acc = {};
#pragma unroll
  for (int kk = 0; kk < 4; ++kk) {
    bf16x8 bf =
        *(const bf16x8*)(bl + c * 128 + ((kk * 32 + h * 16) ^ ((c & 7) << 4)));
    acc = __builtin_amdgcn_mfma_f32_32x32x16_bf16(af[kk], bf, acc, 0, 0, 0);
  }
  const float bc = pb[c];

  char* myt = tl + wid * 4096;
#pragma unroll
  for (int p = 0; p < 8; ++p) {
    const int r = 2 * p;
    const int n = (r & 3) + 8 * (r >> 2) + 4 * h;
    *(float2*)(myt + l31 * 128 + n * 4) =
        make_float2(acc[r] + bc, acc[r + 1] + bc);
  }
  __syncthreads();
#pragma unroll
  for (int u = 0; u < 4; ++u) {
    const int chunk = lane * 4 + u;
    const int cc = chunk >> 3, cq = chunk & 7;
    const float4 vv = *(const float4*)(myt + cc * 128 + cq * 16);
    *(float4*)(out + ((size_t)b * C + wid * 32 + cc) * N + n0 + cq * 4) = vv;
  }
}

// ---------------------------------------------------------------------------
extern "C" void kernel_launch(void* const* d_in, const int* in_sizes, int n_in,
                              void* d_out, int out_size, void* d_ws, size_t ws_size,
                              hipStream_t stream) {
  const float* x      = (const float*)d_in[0];
  const float* qkv_w  = (const float*)d_in[1];
  const float* qkv_b  = (const float*)d_in[2];
  const float* proj_w = (const float*)d_in[3];
  const float* proj_b = (const float*)d_in[4];
  // d_in[5..8] (gate MLP) intentionally unused — see header note.
  unsigned short* qb     = (unsigned short*)d_ws;
  unsigned short* kb     = qb + KB_OFF;
  unsigned short* vtb    = qb + VT_OFF;
  unsigned short* part_o = qb + PO_OFF_U;
  float* part_l = (float*)d_ws + PL_OFF_F;
  float* out = (float*)d_out;

  qkv_mfma_kernel<<<dim3(N / 64, B, 3), 256, 0, stream>>>(
      x, qkv_w, qkv_b, qb, kb, vtb);
  attn_mfma_kernel<<<dim3(N / 128, MSA, B * NH), 256, 0, stream>>>(
      qb, kb, vtb, part_o, part_l);
  proj_mfma_kernel<<<dim3(N / 32, B), 128, 0, stream>>>(
      part_o, part_l, proj_w, proj_b, out);
}

// Round 19
// 38.591 us; speedup vs baseline: 1.0098x; 1.0098x over previous
//
#include <hip/hip_runtime.h>
#include <cstdint>

// EdgeGateAttention, MI355X — round 19: 2 q-tiles per wave (ILP doubling).
// r18 post-mortem: occupancy push (MSA=8 + (256,5) + V-direct) regressed
// (38.97 vs r14's 35.05).  attn floor ~22-26us across 7 variants, all pipes
// <25% — per-wave serial chain is the bound; waves don't cover it.  This
// round doubles INDEPENDENT work per wave: 64 q rows/wave, one shared K-frag
// feeds two QK^T MFMAs (two independent st chains), shared V frags feed both
// PV pairs.  Grid (N/256, MSA=8, 8) = 1024 blocks, 4 waves/SIMD, (256,4).
// K: MT=128 LDS dbuf (4 staging VGPR).  V: direct from global (r15 layout).
//
// Gate skip (validated r1): gate renorm makes it identity to O(1e-8).
// Softmax: raw v_exp_f32, no max subtraction; 0.25*log2(e) folded into Q.
// l from ones-column (d=16) of the PV MFMA.

namespace {
constexpr int B  = 2;
constexpr int C  = 64;
constexpr int NH = 4;
constexpr int HD = 16;
constexpr int N  = 4096;
constexpr int MSA = 8;              // attention m-split

constexpr size_t QKV1     = (size_t)B * NH * N * HD;        // 524288
constexpr size_t KB_OFF   = QKV1;
constexpr size_t VT_OFF   = 2 * QKV1;
constexpr size_t PO_OFF_U = 3 * QKV1;                       // ushort idx
constexpr size_t PO_SZ    = (size_t)B * NH * MSA * N * HD;  // 4194304 ushorts
constexpr size_t PL_OFF_F = (PO_OFF_U + PO_SZ) / 2;         // float idx
constexpr float QSCALE = 0.36067376022224085f;              // 0.25 * log2(e)
}

typedef short bf16x8 __attribute__((ext_vector_type(8)));
typedef float f32x16 __attribute__((ext_vector_type(16)));
typedef int   i32x4  __attribute__((ext_vector_type(4)));

__device__ __forceinline__ unsigned short f2bf(float f) {  // RNE f32->bf16
  unsigned u = __float_as_uint(f);
  u = (u + 0x7fffu + ((u >> 16) & 1u)) >> 16;
  return (unsigned short)u;
}
__device__ __forceinline__ int cvtpk(float lo, float hi) {
  int r;
  asm("v_cvt_pk_bf16_f32 %0, %1, %2" : "=v"(r) : "v"(lo), "v"(hi));
  return r;
}
__device__ __forceinline__ float fexp2(float x) {  // raw v_exp_f32
#if __has_builtin(__builtin_amdgcn_exp2f)
  return __builtin_amdgcn_exp2f(x);
#else
  float r;
  asm("v_exp_f32 %0, %1" : "=v"(r) : "v"(x));
  return r;
#endif
}
__device__ __forceinline__ float frcp(float x) {
#if __has_builtin(__builtin_amdgcn_rcpf)
  return __builtin_amdgcn_rcpf(x);
#else
  float r;
  asm("v_rcp_f32 %0, %1" : "=v"(r) : "v"(x));
  return r;
#endif
}
__device__ __forceinline__ void plswap(int a, int b, int h, int& x, int& y) {
#if __has_builtin(__builtin_amdgcn_permlane32_swap)
  (void)h;
  auto r = __builtin_amdgcn_permlane32_swap(a, b, false, false);
  x = r[0]; y = r[1];
#else
  const int ea = __shfl_xor(a, 32), eb = __shfl_xor(b, 32);
  x = h ? eb : a;
  y = h ? b : ea;
#endif
}

// ---------------------------------------------------------------------------
// Kernel 1: QKV GEMM (r15, proven).  Grid (N/64, B, 3): z=0 q, 1 k, 2 v.
// k: chunk order [bh][n/32][half][n%32] (16B chunks).
// v: chunk order [bh][n/32][sub(4 m-octets)][d(16)][8m] (16B chunks).
// ---------------------------------------------------------------------------
__global__ __launch_bounds__(256) void qkv_mfma_kernel(
    const float* __restrict__ x, const float* __restrict__ w,
    const float* __restrict__ bias, unsigned short* __restrict__ qb,
    unsigned short* __restrict__ kb, unsigned short* __restrict__ vtb) {
  __shared__ char wl[64 * 128];   // W slice bf16, byte (2c)^((j&7)<<4)
  __shared__ char tl[4 * 2048];   // per-wave transpose buffers
  const int tid = threadIdx.x;
  const int lane = tid & 63, wid = tid >> 6;
  const int l31 = lane & 31, h = lane >> 5;
  const int nw = wid >> 1, jw = wid & 1;
  const int b = blockIdx.y, n0 = blockIdx.x * 64, z = blockIdx.z;

#pragma unroll
  for (int k = 0; k < 8; ++k) {   // stage W slice (64 rows x 64 c)
    const int p = tid + k * 256;
    const int j = p >> 5, c2 = (p & 31) * 2;
    const float2 wv = *(const float2*)(w + ((size_t)z * 64 + j) * 64 + c2);
    *(int*)(wl + j * 128 + ((2 * c2) ^ ((j & 7) << 4))) = cvtpk(wv.x, wv.y);
  }

  const int nA = n0 + nw * 32 + l31;
  bf16x8 af[4];
#pragma unroll
  for (int kk = 0; kk < 4; ++kk) {  // A-frags from global (coalesced over n)
    float e[8];
#pragma unroll
    for (int i = 0; i < 8; ++i)
      e[i] = x[((size_t)b * C + kk * 16 + h * 8 + i) * N + nA];
    i32x4 pk = {cvtpk(e[0], e[1]), cvtpk(e[2], e[3]),
                cvtpk(e[4], e[5]), cvtpk(e[6], e[7])};
    af[kk] = __builtin_bit_cast(bf16x8, pk);
  }
  __syncthreads();

  const int j = jw * 32 + l31;      // j within z-slice (0..63)
  f32x16 acc = {};
#pragma unroll
  for (int kk = 0; kk < 4; ++kk) {
    bf16x8 bf =
        *(const bf16x8*)(wl + j * 128 + ((kk * 32 + h * 16) ^ ((j & 7) << 4)));
    acc = __builtin_amdgcn_mfma_f32_32x32x16_bf16(af[kk], bf, acc, 0, 0, 0);
  }
  const float bj = bias[z * 64 + j];
  char* myt = tl + wid * 2048;
  const int mt32 = (n0 >> 5) + nw;    // 32-row tile index in N

  if (z < 2) {  // q/k; LDS [32n][32j] bf16 (rows 64B)
    const float sc = (z == 0) ? QSCALE : 1.0f;
#pragma unroll
    for (int r = 0; r < 16; ++r) {
      const int n = (r & 3) + 8 * (r >> 2) + 4 * h;
      *(unsigned short*)(myt + n * 64 + l31 * 2) = f2bf((acc[r] + bj) * sc);
    }
#pragma unroll
    for (int u = 0; u < 2; ++u) {   // 128 chunks: (n, 8-j group)
      const int chunk = lane * 2 + u;
      const int n = chunk >> 2, c = chunk & 3;
      const uint4 vv = *(const uint4*)(myt + n * 64 + c * 16);
      const int jj = jw * 32 + c * 8;          // j-offset in 0..63
      const int hh = jj >> 4, half = (jj >> 3) & 1;
      const int bh = b * NH + hh;
      if (z == 0) {   // q: [bh][n][16]
        *(uint4*)(qb + ((size_t)bh * N + n0 + nw * 32 + n) * HD + half * 8) = vv;
      } else {        // k: chunk order [bh][tile32][half][r]
        const size_t ck = (size_t)bh * 8192 + (size_t)mt32 * 64 + half * 32 + n;
        *(uint4*)(kb + ck * 8) = vv;
      }
    }
  } else {      // v: chunk order [bh][tile32][sub][d][8m]; LDS [32j][32n]
#pragma unroll
    for (int p = 0; p < 8; ++p) {
      const int r = 2 * p;
      const int n = (r & 3) + 8 * (r >> 2) + 4 * h;  // even
      *(int*)(myt + l31 * 64 + n * 2) = cvtpk(acc[r] + bj, acc[r + 1] + bj);
    }
#pragma unroll
    for (int u = 0; u < 2; ++u) {   // 128 chunks: (j, 8-n octet)
      const int chunk = lane * 2 + u;
      const int jj = chunk >> 2, c = chunk & 3;   // c = m-octet (sub)
      const uint4 vv = *(const uint4*)(myt + jj * 64 + c * 16);
      const int vj = jw * 32 + jj;             // 0..63
      const int hh = vj >> 4, hd = vj & 15;
      const size_t ck =
          (((size_t)(b * NH + hh) * 128 + mt32) * 4 + c) * 16 + hd;
      *(uint4*)(vtb + ck * 8) = vv;
    }
  }
}

// ---------------------------------------------------------------------------
// Kernel 2: attention, 2 q-tiles per wave.  Grid (N/256, MSA=8, B*NH) =
// 1024 blocks, 4 waves x 64 q-rows, (256,4).
// K: MT=128 LDS dbuf; one kf read feeds TWO QK^T MFMAs (independent chains).
// V: direct from global (r15 chunk layout), shared by both PV pairs.
// ---------------------------------------------------------------------------
__global__ __launch_bounds__(256, 4) void attn_mfma_kernel(
    const unsigned short* __restrict__ qb, const unsigned short* __restrict__ kb,
    const unsigned short* __restrict__ vtb, unsigned short* __restrict__ part_o,
    float* __restrict__ part_l) {
  __shared__ char ldsb[8192];     // 2 x 4KB K-tile buffers; epilogue reuse
  const int tid  = threadIdx.x;
  const int lane = tid & 63;
  const int wid  = tid >> 6;
  const int l31  = lane & 31;
  const int h    = lane >> 5;
  const int bh = blockIdx.z;
  const int ms = blockIdx.y;
  const int q0 = blockIdx.x * 256 + wid * 64;
  const int m0 = ms * (N / MSA);       // 512-row m-chunk
  constexpr int NT = (N / MSA) / 128;  // 4 K-tiles of 128 m

  bf16x8 qfA, qfB;
  {
    const uint4 qa =
        *(const uint4*)(qb + (((size_t)bh * N) + q0 + l31) * HD + h * 8);
    const uint4 qv =
        *(const uint4*)(qb + (((size_t)bh * N) + q0 + 32 + l31) * HD + h * 8);
    qfA = __builtin_bit_cast(bf16x8, qa);
    qfB = __builtin_bit_cast(bf16x8, qv);
  }
  // K chunk base for (bh, m0): tile t = 256 chunks (4KB), LINEAR.
  const unsigned short* kgp =
      kb + ((size_t)bh * 8192 + (size_t)(m0 >> 5) * 64) * 8;
  // V per-lane pointer (d = l31 < 16): stride 512 ushorts per 32-m iter.
  const unsigned short* vp =
      vtb + ((((size_t)bh * 128 + (m0 >> 5)) * 4 + h) * 16 + l31) * 8;

  {  // prologue: stage K tile 0 (4KB)
    *(uint4*)(ldsb + tid * 16) = *(const uint4*)(kgp + (size_t)tid * 8);
  }
  __syncthreads();

  const int onef = (l31 == HD) ? 0x3F803F80 : 0;
  const i32x4 onev = {onef, onef, onef, onef};
  const bf16x8 vcst = __builtin_bit_cast(bf16x8, onev);

  f32x16 accA = {}, accB = {};
  int cur = 0;
  for (int t = 0; t < NT; ++t) {
    uint4 k0{};
    const bool pre = (t + 1 < NT);
    if (pre)  // issue next K tile load; hides under this tile's compute
      k0 = *(const uint4*)(kgp + ((size_t)(t + 1) * 256 + tid) * 8);
    const char* kbase = ldsb + cur * 4096;
#pragma unroll
    for (int cc = 0; cc < 4; ++cc) {
      const int it = t * 4 + cc;
      // conflict-free: half-wave reads 512B contiguous
      bf16x8 kf = *(const bf16x8*)(kbase + (cc * 64 + h * 32 + l31) * 16);
      f32x16 zv = {};
      f32x16 stA = __builtin_amdgcn_mfma_f32_32x32x16_bf16(kf, qfA, zv, 0, 0, 0);
      f32x16 stB = __builtin_amdgcn_mfma_f32_32x32x16_bf16(kf, qfB, zv, 0, 0, 0);
      bf16x8 vf1, vf2;
      if (l31 < HD) {
        vf1 = *(const bf16x8*)(vp + (size_t)it * 512);
        vf2 = *(const bf16x8*)(vp + (size_t)it * 512 + 256);
      } else {  // d=16: ones column -> acc col 16 = sum(p) = l
        vf1 = vcst;
        vf2 = vcst;
      }
      {  // chain A
        int dw[8];
#pragma unroll
        for (int jj = 0; jj < 8; ++jj)
          dw[jj] = cvtpk(fexp2(stA[2 * jj]), fexp2(stA[2 * jj + 1]));
        int w0, w1, w2, w3, w4, w5, w6, w7;
        plswap(dw[0], dw[2], h, w0, w2);
        plswap(dw[1], dw[3], h, w1, w3);
        plswap(dw[4], dw[6], h, w4, w6);
        plswap(dw[5], dw[7], h, w5, w7);
        const i32x4 a1 = {w0, w1, w2, w3};
        const i32x4 a2 = {w4, w5, w6, w7};
        accA = __builtin_amdgcn_mfma_f32_32x32x16_bf16(
            __builtin_bit_cast(bf16x8, a1), vf1, accA, 0, 0, 0);
        accA = __builtin_amdgcn_mfma_f32_32x32x16_bf16(
            __builtin_bit_cast(bf16x8, a2), vf2, accA, 0, 0, 0);
      }
      {  // chain B (independent of A; dovetails in the issue slots)
        int dw[8];
#pragma unroll
        for (int jj = 0; jj < 8; ++jj)
          dw[jj] = cvtpk(fexp2(stB[2 * jj]), fexp2(stB[2 * jj + 1]));
        int w0, w1, w2, w3, w4, w5, w6, w7;
        plswap(dw[0], dw[2], h, w0, w2);
        plswap(dw[1], dw[3], h, w1, w3);
        plswap(dw[4], dw[6], h, w4, w6);
        plswap(dw[5], dw[7], h, w5, w7);
        const i32x4 a1 = {w0, w1, w2, w3};
        const i32x4 a2 = {w4, w5, w6, w7};
        accB = __builtin_amdgcn_mfma_f32_32x32x16_bf16(
            __builtin_bit_cast(bf16x8, a1), vf1, accB, 0, 0, 0);
        accB = __builtin_amdgcn_mfma_f32_32x32x16_bf16(
            __builtin_bit_cast(bf16x8, a2), vf2, accB, 0, 0, 0);
      }
    }
    if (pre) *(uint4*)(ldsb + (cur ^ 1) * 4096 + tid * 16) = k0;
    __syncthreads();
    cur ^= 1;
  }

  const size_t pbase = ((size_t)bh * MSA + ms) * N + q0;
  if (l31 == HD) {
#pragma unroll
    for (int r = 0; r < 16; ++r) {
      const int q = (r & 3) + 8 * (r >> 2) + 4 * h;
      part_l[pbase + q] = accA[r];
      part_l[pbase + 32 + q] = accB[r];
    }
  }
  char* myt = ldsb + wid * 2048;    // 2 x [32q][16d] bf16 per wave (reuse)
  if (l31 < HD) {
#pragma unroll
    for (int r = 0; r < 16; ++r) {
      const int q = (r & 3) + 8 * (r >> 2) + 4 * h;
      *(unsigned short*)(myt + q * 32 + l31 * 2) = f2bf(accA[r]);
      *(unsigned short*)(myt + 1024 + q * 32 + l31 * 2) = f2bf(accB[r]);
    }
  }
  __syncthreads();
  const int qr = lane >> 1, half = lane & 1;
  const uint4 vA = *(const uint4*)(myt + qr * 32 + half * 16);
  *(uint4*)(part_o + (pbase + qr) * HD + half * 8) = vA;
  const uint4 vB = *(const uint4*)(myt + 1024 + qr * 32 + half * 16);
  *(uint4*)(part_o + (pbase + 32 + qr) * HD + half * 8) = vB;
}

// ---------------------------------------------------------------------------
// Kernel 3: fused combine + projection.  Grid (N/32, B); MSA=8 combine.
// ---------------------------------------------------------------------------
__global__ __launch_bounds__(128) void proj_mfma_kernel(
    const unsigned short* __restrict__ part_o, const float* __restrict__ part_l,
    const float* __restrict__ pw, const float* __restrict__ pb,
    float* __restrict__ out) {
  __shared__ char al[32 * 128];
  __shared__ char bl[64 * 128];
  __shared__ char tl[2 * 4096];
  __shared__ float linv[128];
  const int tid = threadIdx.x;
  const int lane = tid & 63, wid = tid >> 6;
  const int l31 = lane & 31, h = lane >> 5;
  const int b = blockIdx.y, n0 = blockIdx.x * 32;

  {
    const int hh = tid >> 5, n = tid & 31;
    const size_t base = ((size_t)(b * NH + hh) * MSA) * N + n0 + n;
    float l = 0.f;
#pragma unroll
    for (int ms = 0; ms < MSA; ++ms) l += part_l[base + (size_t)ms * N];
    linv[tid] = frcp(l);
  }
#pragma unroll
  for (int k = 0; k < 16; ++k) {
    const int p = tid + k * 128;
    const int cR = p >> 5, d2 = (p & 31) * 2;
    const float2 wv = *(const float2*)(pw + cR * 64 + d2);
    *(int*)(bl + cR * 128 + ((2 * d2) ^ ((cR & 7) << 4))) = cvtpk(wv.x, wv.y);
  }
  __syncthreads();

#pragma unroll
  for (int u = 0; u < 2; ++u) {
    const int chunk = tid * 2 + u;
    const int hh = chunk >> 6, half = (chunk >> 5) & 1, n = chunk & 31;
    const unsigned short* src =
        part_o + (((size_t)(b * NH + hh) * MSA) * N + n0 + n) * HD + half * 8;
    float s[8] = {0.f, 0.f, 0.f, 0.f, 0.f, 0.f, 0.f, 0.f};
#pragma unroll
    for (int ms = 0; ms < MSA; ++ms) {
      const uint4 v = *(const uint4*)(src + (size_t)ms * N * HD);
      const unsigned uu[4] = {v.x, v.y, v.z, v.w};
#pragma unroll
      for (int q = 0; q < 4; ++q) {
        s[2 * q]     += __uint_as_float(uu[q] << 16);
        s[2 * q + 1] += __uint_as_float(uu[q] & 0xffff0000u);
      }
    }
    const float iv = linv[hh * 32 + n];
    const i32x4 pk = {cvtpk(s[0] * iv, s[1] * iv), cvtpk(s[2] * iv, s[3] * iv),
                      cvtpk(s[4] * iv, s[5] * iv), cvtpk(s[6] * iv, s[7] * iv)};
    const int d = hh * 16 + half * 8;
    *(i32x4*)(al + n * 128 + ((2 * d) ^ ((n & 7) << 4))) = pk;
  }
  __syncthreads();

  bf16x8 af[4];
#pragma unroll
  for (int kk = 0; kk < 4; ++kk)
    af[kk] = *(const bf16x8*)(al + l31 * 128 +
                              ((kk * 32 + h * 16) ^ ((l31 & 7) << 4)));
  const int c = wid * 32 + l31;
  f32x16 acc = {};
#pragma unroll
  for (int kk = 0; kk < 4; ++kk) {
    bf16x8 bf =
        *(const bf16x8*)(bl + c * 128 + ((kk * 32 + h * 16) ^ ((c & 7) << 4)));
    acc = __builtin_amdgcn_mfma_f32_32x32x16_bf16(af[kk], bf, acc, 0, 0, 0);
  }
  const float bc = pb[c];

  char* myt = tl + wid * 4096;
#pragma unroll
  for (int p = 0; p < 8; ++p) {
    const int r = 2 * p;
    const int n = (r & 3) + 8 * (r >> 2) + 4 * h;
    *(float2*)(myt + l31 * 128 + n * 4) =
        make_float2(acc[r] + bc, acc[r + 1] + bc);
  }
  __syncthreads();
#pragma unroll
  for (int u = 0; u < 4; ++u) {
    const int chunk = lane * 4 + u;
    const int cc = chunk >> 3, cq = chunk & 7;
    const float4 vv = *(const float4*)(myt + cc * 128 + cq * 16);
    *(float4*)(out + ((size_t)b * C + wid * 32 + cc) * N + n0 + cq * 4) = vv;
  }
}

// ---------------------------------------------------------------------------
extern "C" void kernel_launch(void* const* d_in, const int* in_sizes, int n_in,
                              void* d_out, int out_size, void* d_ws, size_t ws_size,
                              hipStream_t stream) {
  const float* x      = (const float*)d_in[0];
  const float* qkv_w  = (const float*)d_in[1];
  const float* qkv_b  = (const float*)d_in[2];
  const float* proj_w = (const float*)d_in[3];
  const float* proj_b = (const float*)d_in[4];
  // d_in[5..8] (gate MLP) intentionally unused — see header note.
  unsigned short* qb     = (unsigned short*)d_ws;
  unsigned short* kb     = qb + KB_OFF;
  unsigned short* vtb    = qb + VT_OFF;
  unsigned short* part_o = qb + PO_OFF_U;
  float* part_l = (float*)d_ws + PL_OFF_F;
  float* out = (float*)d_out;

  qkv_mfma_kernel<<<dim3(N / 64, B, 3), 256, 0, stream>>>(
      x, qkv_w, qkv_b, qb, kb, vtb);
  attn_mfma_kernel<<<dim3(N / 256, MSA, B * NH), 256, 0, stream>>>(
      qb, kb, vtb, part_o, part_l);
  proj_mfma_kernel<<<dim3(N / 32, B), 128, 0, stream>>>(
      part_o, part_l, proj_w, proj_b, out);
}

// Round 20
// 35.145 us; speedup vs baseline: 1.1088x; 1.0980x over previous
//
#include <hip/hip_runtime.h>
#include <cstdint>

// EdgeGateAttention, MI355X — round 20: deliberate revert to the round-14
// champion (35.05us, best of 19 rounds).  r15 (LDS-free, -2.4), r18
// (occupancy push, -3.9), r19 (2-tile ILP, -3.5) all regressed vs this
// config; the attn hypothesis space reachable with masked counters is
// exhausted.  Config: MSA=4 (1024 blocks, 4 waves/SIMD), MT=256 K+V LDS
// double-buffer, chunk-ordered conflict-free K, software-pipelined inner
// loop, (256,4); bf16 partials; fused combine+proj.
//
// Gate skip (validated r1): gate renorm makes it identity to O(1e-8).
// Softmax: raw v_exp_f32, no max subtraction; 0.25*log2(e) folded into Q.
// l from ones-column (d=16) of the PV MFMA.

namespace {
constexpr int B  = 2;
constexpr int C  = 64;
constexpr int NH = 4;
constexpr int HD = 16;
constexpr int N  = 4096;
constexpr int MSA = 4;              // attention m-split
constexpr int MT  = 256;            // K/V m-tile rows staged in LDS
constexpr int VROW  = 2 * MT + 16;  // 528 B
constexpr int KSZ   = MT * 32;      // 8192 B
constexpr int BUFSZ = KSZ + HD * VROW;  // 16640 B

constexpr size_t QKV1     = (size_t)B * NH * N * HD;        // 524288
constexpr size_t KB_OFF   = QKV1;
constexpr size_t VT_OFF   = 2 * QKV1;
constexpr size_t PO_OFF_U = 3 * QKV1;                       // ushort idx
constexpr size_t PO_SZ    = (size_t)B * NH * MSA * N * HD;  // 2097152 ushorts
constexpr size_t PL_OFF_F = (PO_OFF_U + PO_SZ) / 2;         // float idx
constexpr float QSCALE = 0.36067376022224085f;              // 0.25 * log2(e)
}

typedef short bf16x8 __attribute__((ext_vector_type(8)));
typedef float f32x16 __attribute__((ext_vector_type(16)));
typedef int   i32x4  __attribute__((ext_vector_type(4)));

__device__ __forceinline__ unsigned short f2bf(float f) {  // RNE f32->bf16
  unsigned u = __float_as_uint(f);
  u = (u + 0x7fffu + ((u >> 16) & 1u)) >> 16;
  return (unsigned short)u;
}
__device__ __forceinline__ int cvtpk(float lo, float hi) {
  int r;
  asm("v_cvt_pk_bf16_f32 %0, %1, %2" : "=v"(r) : "v"(lo), "v"(hi));
  return r;
}
__device__ __forceinline__ float fexp2(float x) {  // raw v_exp_f32
#if __has_builtin(__builtin_amdgcn_exp2f)
  return __builtin_amdgcn_exp2f(x);
#else
  float r;
  asm("v_exp_f32 %0, %1" : "=v"(r) : "v"(x));
  return r;
#endif
}
__device__ __forceinline__ float frcp(float x) {
#if __has_builtin(__builtin_amdgcn_rcpf)
  return __builtin_amdgcn_rcpf(x);
#else
  float r;
  asm("v_rcp_f32 %0, %1" : "=v"(r) : "v"(x));
  return r;
#endif
}
__device__ __forceinline__ void plswap(int a, int b, int h, int& x, int& y) {
#if __has_builtin(__builtin_amdgcn_permlane32_swap)
  (void)h;
  auto r = __builtin_amdgcn_permlane32_swap(a, b, false, false);
  x = r[0]; y = r[1];
#else
  const int ea = __shfl_xor(a, 32), eb = __shfl_xor(b, 32);
  x = h ? eb : a;
  y = h ? b : ea;
#endif
}

// ---------------------------------------------------------------------------
// Kernel 1: QKV GEMM.  Grid (N/64, B, 3): z=0 q, 1 k, 2 v.
// k output in LDS-read chunk order [bh][n/32][half][n%32] (16B chunks).
// ---------------------------------------------------------------------------
__global__ __launch_bounds__(256) void qkv_mfma_kernel(
    const float* __restrict__ x, const float* __restrict__ w,
    const float* __restrict__ bias, unsigned short* __restrict__ qb,
    unsigned short* __restrict__ kb, unsigned short* __restrict__ vtb) {
  __shared__ char wl[64 * 128];   // W slice bf16, byte (2c)^((j&7)<<4)
  __shared__ char tl[4 * 2048];   // per-wave transpose buffers
  const int tid = threadIdx.x;
  const int lane = tid & 63, wid = tid >> 6;
  const int l31 = lane & 31, h = lane >> 5;
  const int nw = wid >> 1, jw = wid & 1;
  const int b = blockIdx.y, n0 = blockIdx.x * 64, z = blockIdx.z;

#pragma unroll
  for (int k = 0; k < 8; ++k) {   // stage W slice (64 rows x 64 c)
    const int p = tid + k * 256;
    const int j = p >> 5, c2 = (p & 31) * 2;
    const float2 wv = *(const float2*)(w + ((size_t)z * 64 + j) * 64 + c2);
    *(int*)(wl + j * 128 + ((2 * c2) ^ ((j & 7) << 4))) = cvtpk(wv.x, wv.y);
  }

  const int nA = n0 + nw * 32 + l31;
  bf16x8 af[4];
#pragma unroll
  for (int kk = 0; kk < 4; ++kk) {  // A-frags from global (coalesced over n)
    float e[8];
#pragma unroll
    for (int i = 0; i < 8; ++i)
      e[i] = x[((size_t)b * C + kk * 16 + h * 8 + i) * N + nA];
    i32x4 pk = {cvtpk(e[0], e[1]), cvtpk(e[2], e[3]),
                cvtpk(e[4], e[5]), cvtpk(e[6], e[7])};
    af[kk] = __builtin_bit_cast(bf16x8, pk);
  }
  __syncthreads();

  const int j = jw * 32 + l31;      // j within z-slice (0..63)
  f32x16 acc = {};
#pragma unroll
  for (int kk = 0; kk < 4; ++kk) {
    bf16x8 bf =
        *(const bf16x8*)(wl + j * 128 + ((kk * 32 + h * 16) ^ ((j & 7) << 4)));
    acc = __builtin_amdgcn_mfma_f32_32x32x16_bf16(af[kk], bf, acc, 0, 0, 0);
  }
  const float bj = bias[z * 64 + j];
  char* myt = tl + wid * 2048;

  if (z < 2) {  // q/k; LDS [32n][32j] bf16 (rows 64B)
    const float sc = (z == 0) ? QSCALE : 1.0f;
#pragma unroll
    for (int r = 0; r < 16; ++r) {
      const int n = (r & 3) + 8 * (r >> 2) + 4 * h;
      *(unsigned short*)(myt + n * 64 + l31 * 2) = f2bf((acc[r] + bj) * sc);
    }
#pragma unroll
    for (int u = 0; u < 2; ++u) {   // 128 chunks: (n, 8-j group)
      const int chunk = lane * 2 + u;
      const int n = chunk >> 2, c = chunk & 3;
      const uint4 vv = *(const uint4*)(myt + n * 64 + c * 16);
      const int jj = jw * 32 + c * 8;          // j-offset in 0..63
      const int hh = jj >> 4, half = (jj >> 3) & 1;
      const int bh = b * NH + hh;
      if (z == 0) {   // q: [bh][n][16]
        *(uint4*)(qb + ((size_t)bh * N + n0 + nw * 32 + n) * HD + half * 8) = vv;
      } else {        // k: chunk order [bh][tile32][half][r]
        const size_t ck = (size_t)bh * 8192 +
                          (size_t)((n0 >> 5) + nw) * 64 + half * 32 + n;
        *(uint4*)(kb + ck * 8) = vv;
      }
    }
  } else {      // v -> transposed [bh][d][N]; LDS [32j][32n] bf16
#pragma unroll
    for (int p = 0; p < 8; ++p) {
      const int r = 2 * p;
      const int n = (r & 3) + 8 * (r >> 2) + 4 * h;  // even
      *(int*)(myt + l31 * 64 + n * 2) = cvtpk(acc[r] + bj, acc[r + 1] + bj);
    }
#pragma unroll
    for (int u = 0; u < 2; ++u) {   // 128 chunks: (j, 8-n group)
      const int chunk = lane * 2 + u;
      const int jj = chunk >> 2, c = chunk & 3;
      const uint4 vv = *(const uint4*)(myt + jj * 64 + c * 16);
      const int vj = jw * 32 + jj;             // 0..63
      const int hh = vj >> 4, hd = vj & 15;
      *(uint4*)(vtb + ((size_t)(b * NH + hh) * HD + hd) * N + n0 + nw * 32 +
                c * 8) = vv;
    }
  }
}

// ---------------------------------------------------------------------------
// Kernel 2: attention, software-pipelined.  Grid (N/128, MSA, B*NH) = 1024.
// Conflict-free K path (chunk-ordered kb); next iter's K read + QK^T MFMA
// issued before current iter's exp/pack/PV processing.
// ---------------------------------------------------------------------------
__global__ __launch_bounds__(256, 4) void attn_mfma_kernel(
    const unsigned short* __restrict__ qb, const unsigned short* __restrict__ kb,
    const unsigned short* __restrict__ vtb, unsigned short* __restrict__ part_o,
    float* __restrict__ part_l) {
  __shared__ uint4 ldsq[2 * BUFSZ / 16];
  char* ldsb = (char*)ldsq;
  const int tid  = threadIdx.x;
  const int lane = tid & 63;
  const int wid  = tid >> 6;
  const int l31  = lane & 31;
  const int h    = lane >> 5;
  const int bh = blockIdx.z;
  const int ms = blockIdx.y;
  const int q0 = blockIdx.x * 128 + wid * 32;
  const int m0 = ms * (N / MSA);
  constexpr int nt = (N / MSA) / MT;  // 4

  bf16x8 qf;
  {
    const uint4 qv =
        *(const uint4*)(qb + (((size_t)bh * N) + q0 + l31) * HD + h * 8);
    qf = __builtin_bit_cast(bf16x8, qv);
  }
  const unsigned short* kgp = kb + ((size_t)bh * 8192 + (m0 >> 5) * 64) * 8;
  const unsigned short* vgp = vtb + (size_t)bh * HD * N + m0;
  const int d0 = tid >> 5, c0 = tid & 31;
  const int d1 = d0 + 8;

  {
    uint4 k0 = *(const uint4*)(kgp + (size_t)tid * 8);
    uint4 k1 = *(const uint4*)(kgp + (size_t)(tid + 256) * 8);
    uint4 v0 = *(const uint4*)(vgp + (size_t)d0 * N + c0 * 8);
    uint4 v1 = *(const uint4*)(vgp + (size_t)d1 * N + c0 * 8);
    *(uint4*)(ldsb + tid * 16) = k0;
    *(uint4*)(ldsb + (tid + 256) * 16) = k1;
    *(uint4*)(ldsb + KSZ + d0 * VROW + c0 * 16) = v0;
    *(uint4*)(ldsb + KSZ + d1 * VROW + c0 * 16) = v1;
  }
  __syncthreads();

  // ones-column constant for lanes l31 >= 16 (l from PV accumulation)
  const int onef = (l31 == HD) ? 0x3F803F80 : 0;
  const i32x4 onev = {onef, onef, onef, onef};
  const bf16x8 vcst = __builtin_bit_cast(bf16x8, onev);

  f32x16 acc = {};
  int cur = 0;
  for (int t = 0; t < nt; ++t) {
    uint4 k0{}, k1{}, v0{}, v1{};
    const bool pre = (t + 1 < nt);
    if (pre) {
      const unsigned short* kt = kgp + (size_t)(t + 1) * 512 * 8;
      const unsigned short* vt = vgp + (t + 1) * MT;
      k0 = *(const uint4*)(kt + (size_t)tid * 8);
      k1 = *(const uint4*)(kt + (size_t)(tid + 256) * 8);
      v0 = *(const uint4*)(vt + (size_t)d0 * N + c0 * 8);
      v1 = *(const uint4*)(vt + (size_t)d1 * N + c0 * 8);
    }
    const char* kbase = ldsb + cur * BUFSZ;
    const char* vbase = kbase + KSZ;

    // pipeline prologue: K-frag 0 + its QK^T
    bf16x8 kf = *(const bf16x8*)(kbase + (h * 32 + l31) * 16);
    f32x16 zv = {};
    f32x16 stn = __builtin_amdgcn_mfma_f32_32x32x16_bf16(kf, qf, zv, 0, 0, 0);

#pragma unroll
    for (int cc = 0; cc < MT / 32; ++cc) {
      const f32x16 st = stn;
      if (cc + 1 < MT / 32) {   // issue next K read + QK^T before processing
        bf16x8 kf2 =
            *(const bf16x8*)(kbase + ((cc + 1) * 64 + h * 32 + l31) * 16);
        stn = __builtin_amdgcn_mfma_f32_32x32x16_bf16(kf2, qf, zv, 0, 0, 0);
      }
      // V fragments (independent of st) — issue early
      bf16x8 vf1, vf2;
      if (l31 < HD) {
        const char* vrow = vbase + l31 * VROW + cc * 64 + h * 16;
        vf1 = *(const bf16x8*)(vrow);
        vf2 = *(const bf16x8*)(vrow + 32);
      } else {
        vf1 = vcst;
        vf2 = vcst;
      }
      int dw[8];
#pragma unroll
      for (int jj = 0; jj < 8; ++jj)   // exp -> pack, pairwise (short lives)
        dw[jj] = cvtpk(fexp2(st[2 * jj]), fexp2(st[2 * jj + 1]));
      int w0, w1, w2, w3, w4, w5, w6, w7;
      plswap(dw[0], dw[2], h, w0, w2);
      plswap(dw[1], dw[3], h, w1, w3);
      plswap(dw[4], dw[6], h, w4, w6);
      plswap(dw[5], dw[7], h, w5, w7);
      const i32x4 a1 = {w0, w1, w2, w3};
      const i32x4 a2 = {w4, w5, w6, w7};
      acc = __builtin_amdgcn_mfma_f32_32x32x16_bf16(
          __builtin_bit_cast(bf16x8, a1), vf1, acc, 0, 0, 0);
      acc = __builtin_amdgcn_mfma_f32_32x32x16_bf16(
          __builtin_bit_cast(bf16x8, a2), vf2, acc, 0, 0, 0);
    }
    if (pre) {
      char* nb = ldsb + (cur ^ 1) * BUFSZ;
      *(uint4*)(nb + tid * 16) = k0;
      *(uint4*)(nb + (tid + 256) * 16) = k1;
      *(uint4*)(nb + KSZ + d0 * VROW + c0 * 16) = v0;
      *(uint4*)(nb + KSZ + d1 * VROW + c0 * 16) = v1;
    }
    __syncthreads();
    cur ^= 1;
  }

  const size_t pbase = ((size_t)bh * MSA + ms) * N + q0;
  if (l31 == HD) {
#pragma unroll
    for (int r = 0; r < 16; ++r)
      part_l[pbase + (r & 3) + 8 * (r >> 2) + 4 * h] = acc[r];
  }
  char* myt = ldsb + wid * 1024;
  if (l31 < HD) {
#pragma unroll
    for (int r = 0; r < 16; ++r) {
      const int q = (r & 3) + 8 * (r >> 2) + 4 * h;
      *(unsigned short*)(myt + q * 32 + l31 * 2) = f2bf(acc[r]);
    }
  }
  __syncthreads();
  const int qr = lane >> 1, half = lane & 1;
  const uint4 vv = *(const uint4*)(myt + qr * 32 + half * 16);
  *(uint4*)(part_o + (pbase + qr) * HD + half * 8) = vv;
}

// ---------------------------------------------------------------------------
// Kernel 3: fused combine + projection.  Grid (N/32, B), 128 thr / 2 waves.
// ---------------------------------------------------------------------------
__global__ __launch_bounds__(128) void proj_mfma_kernel(
    const unsigned short* __restrict__ part_o, const float* __restrict__ part_l,
    const float* __restrict__ pw, const float* __restrict__ pb,
    float* __restrict__ out) {
  __shared__ char al[32 * 128];
  __shared__ char bl[64 * 128];
  __shared__ char tl[2 * 4096];
  __shared__ float linv[128];
  const int tid = threadIdx.x;
  const int lane = tid & 63, wid = tid >> 6;
  const int l31 = lane & 31, h = lane >> 5;
  const int b = blockIdx.y, n0 = blockIdx.x * 32;

  {
    const int hh = tid >> 5, n = tid & 31;
    const size_t base = ((size_t)(b * NH + hh) * MSA) * N + n0 + n;
    float l = 0.f;
#pragma unroll
    for (int ms = 0; ms < MSA; ++ms) l += part_l[base + (size_t)ms * N];
    linv[tid] = frcp(l);
  }
#pragma unroll
  for (int k = 0; k < 16; ++k) {
    const int p = tid + k * 128;
    const int cR = p >> 5, d2 = (p & 31) * 2;
    const float2 wv = *(const float2*)(pw + cR * 64 + d2);
    *(int*)(bl + cR * 128 + ((2 * d2) ^ ((cR & 7) << 4))) = cvtpk(wv.x, wv.y);
  }
  __syncthreads();

#pragma unroll
  for (int u = 0; u < 2; ++u) {
    const int chunk = tid * 2 + u;
    const int hh = chunk >> 6, half = (chunk >> 5) & 1, n = chunk & 31;
    const unsigned short* src =
        part_o + (((size_t)(b * NH + hh) * MSA) * N + n0 + n) * HD + half * 8;
    float s[8] = {0.f, 0.f, 0.f, 0.f, 0.f, 0.f, 0.f, 0.f};
#pragma unroll
    for (int ms = 0; ms < MSA; ++ms) {
      const uint4 v = *(const uint4*)(src + (size_t)ms * N * HD);
      const unsigned uu[4] = {v.x, v.y, v.z, v.w};
#pragma unroll
      for (int q = 0; q < 4; ++q) {
        s[2 * q]     += __uint_as_float(uu[q] << 16);
        s[2 * q + 1] += __uint_as_float(uu[q] & 0xffff0000u);
      }
    }
    const float iv = linv[hh * 32 + n];
    const i32x4 pk = {cvtpk(s[0] * iv, s[1] * iv), cvtpk(s[2] * iv, s[3] * iv),
                      cvtpk(s[4] * iv, s[5] * iv), cvtpk(s[6] * iv, s[7] * iv)};
    const int d = hh * 16 + half * 8;
    *(i32x4*)(al + n * 128 + ((2 * d) ^ ((n & 7) << 4))) = pk;
  }
  __syncthreads();

  bf16x8 af[4];
#pragma unroll
  for (int kk = 0; kk < 4; ++kk)
    af[kk] = *(const bf16x8*)(al + l31 * 128 +
                              ((kk * 32 + h * 16) ^ ((l31 & 7) << 4)));
  const int c = wid * 32 + l31;
  f32x16 acc = {};
#pragma unroll
  for (int kk = 0; kk < 4; ++kk) {
    bf16x8 bf =
        *(const bf16x8*)(bl + c * 128 + ((kk * 32 + h * 16) ^ ((c & 7) << 4)));
    acc = __builtin_amdgcn_mfma_f32_32x32x16_bf16(af[kk], bf, acc, 0, 0, 0);
  }
  const float bc = pb[c];

  char* myt = tl + wid * 4096;
#pragma unroll
  for (int p = 0; p < 8; ++p) {
    const int r = 2 * p;
    const int n = (r & 3) + 8 * (r >> 2) + 4 * h;
    *(float2*)(myt + l31 * 128 + n * 4) =
        make_float2(acc[r] + bc, acc[r + 1] + bc);
  }
  __syncthreads();
#pragma unroll
  for (int u = 0; u < 4; ++u) {
    const int chunk = lane * 4 + u;
    const int cc = chunk >> 3, cq = chunk & 7;
    const float4 vv = *(const float4*)(myt + cc * 128 + cq * 16);
    *(float4*)(out + ((size_t)b * C + wid * 32 + cc) * N + n0 + cq * 4) = vv;
  }
}

// ---------------------------------------------------------------------------
extern "C" void kernel_launch(void* const* d_in, const int* in_sizes, int n_in,
                              void* d_out, int out_size, void* d_ws, size_t ws_size,
                              hipStream_t stream) {
  const float* x      = (const float*)d_in[0];
  const float* qkv_w  = (const float*)d_in[1];
  const float* qkv_b  = (const float*)d_in[2];
  const float* proj_w = (const float*)d_in[3];
  const float* proj_b = (const float*)d_in[4];
  // d_in[5..8] (gate MLP) intentionally unused — see header note.
  unsigned short* qb     = (unsigned short*)d_ws;
  unsigned short* kb     = qb + KB_OFF;
  unsigned short* vtb    = qb + VT_OFF;
  unsigned short* part_o = qb + PO_OFF_U;
  float* part_l = (float*)d_ws + PL_OFF_F;
  float* out = (float*)d_out;

  qkv_mfma_kernel<<<dim3(N / 64, B, 3), 256, 0, stream>>>(
      x, qkv_w, qkv_b, qb, kb, vtb);
  attn_mfma_kernel<<<dim3(N / 128, MSA, B * NH), 256, 0, stream>>>(
      qb, kb, vtb, part_o, part_l);
  proj_mfma_kernel<<<dim3(N / 32, B), 128, 0, stream>>>(
      part_o, part_l, proj_w, proj_b, out);
}